// Round 3
// baseline (108.881 us; speedup 1.0000x reference)
//
#include <hip/hip_runtime.h>

#define WAVE 64
#define WPB 4
#define BLOCK (WAVE * WPB)

// s = (x + OFFSETS[argmin_o |euc_xt - cell@(x+off_o)|]) - x_tilde  for atom n.
// Incremental: r = cell@xt - cell@x; d_o = r - (dx*col0 + dy*col1 + dz*col2).
__device__ __forceinline__ void compute_s(const float c[9],
                                          const float* __restrict__ x,
                                          const float* __restrict__ xt,
                                          int n, float& s0, float& s1, float& s2) {
  const float x0 = x[3 * n + 0], x1 = x[3 * n + 1], x2 = x[3 * n + 2];
  const float t0 = xt[3 * n + 0], t1 = xt[3 * n + 1], t2 = xt[3 * n + 2];
  const float e0 = c[0] * t0 + c[1] * t1 + c[2] * t2;
  const float e1 = c[3] * t0 + c[4] * t1 + c[5] * t2;
  const float e2 = c[6] * t0 + c[7] * t1 + c[8] * t2;
  const float b0 = c[0] * x0 + c[1] * x1 + c[2] * x2;
  const float b1 = c[3] * x0 + c[4] * x1 + c[5] * x2;
  const float b2 = c[6] * x0 + c[7] * x1 + c[8] * x2;
  const float r0 = e0 - b0, r1 = e1 - b1, r2 = e2 - b2;

  float best = 3.4e38f;
  int bo = 0;
#pragma unroll
  for (int i = 0; i < 3; ++i) {
    const float di = (float)(i - 1);
    const float p0 = r0 - di * c[0], p1 = r1 - di * c[3], p2 = r2 - di * c[6];
#pragma unroll
    for (int j = 0; j < 3; ++j) {
      const float dj = (float)(j - 1);
      const float q0 = p0 - dj * c[1], q1 = p1 - dj * c[4], q2 = p2 - dj * c[7];
#pragma unroll
      for (int k = 0; k < 3; ++k) {
        const float dk = (float)(k - 1);
        const float u0 = q0 - dk * c[2], u1 = q1 - dk * c[5], u2 = q2 - dk * c[8];
        const float d = u0 * u0 + u1 * u1 + u2 * u2;
        const int o = 9 * i + 3 * j + k;
        if (d < best) { best = d; bo = o; }  // strict < => first-min, like jnp.argmin
      }
    }
  }
  s0 = x0 + (float)(bo / 9 - 1) - t0;
  s1 = x1 + (float)((bo / 3) % 3 - 1) - t1;
  s2 = x2 + (float)(bo % 3 - 1) - t2;
}

__device__ __forceinline__ float wave_sum(float v) {
#pragma unroll
  for (int m = 32; m >= 1; m >>= 1) v += __shfl_xor(v, m);
  return v;
}

// 4 waves/block, one structure per wave. Fused final reduction via last-block ticket.
__global__ __launch_bounds__(BLOCK) void mdl_main(const float* __restrict__ cell,
                                                  const float* __restrict__ x,
                                                  const float* __restrict__ xt,
                                                  const int* __restrict__ na,
                                                  const int* __restrict__ starts,
                                                  float* __restrict__ partial,
                                                  int* __restrict__ counter,
                                                  float* __restrict__ out,
                                                  int B, int N) {
  __shared__ float wpart[WPB];
  const int wid = threadIdx.x / WAVE;
  const int tid = threadIdx.x % WAVE;
  // wave-uniform structure index -> SGPR so cell/starts/na become s_loads
  const int b = __builtin_amdgcn_readfirstlane(blockIdx.x * WPB + wid);

  float part = 0.f;
  if (b < B) {
    const int start = starts[b];
    const int count = na[b];

    float c[9];
#pragma unroll
    for (int i = 0; i < 9; ++i) c[i] = cell[9 * b + i];

    float sumx = 0.f, sumy = 0.f, sumz = 0.f;
    float s0 = 0.f, s1 = 0.f, s2 = 0.f;
    bool have = false;

    if (count <= WAVE) {
      if (tid < count) {
        compute_s(c, x, xt, start + tid, s0, s1, s2);
        have = true;
        sumx = s0; sumy = s1; sumz = s2;
      }
    } else {
      for (int n = start + tid; n < start + count; n += WAVE) {
        float a0, a1, a2;
        compute_s(c, x, xt, n, a0, a1, a2);
        sumx += a0; sumy += a1; sumz += a2;
      }
    }

    sumx = wave_sum(sumx); sumy = wave_sum(sumy); sumz = wave_sum(sumz);
    const float inv = 1.0f / (float)count;
    const float cx = sumx * inv, cy = sumy * inv, cz = sumz * inv;

    if (count <= WAVE) {
      if (have) part = fabsf(cx - s0) + fabsf(cy - s1) + fabsf(cz - s2);
    } else {
      for (int n = start + tid; n < start + count; n += WAVE) {
        float a0, a1, a2;
        compute_s(c, x, xt, n, a0, a1, a2);
        part += fabsf(cx - a0) + fabsf(cy - a1) + fabsf(cz - a2);
      }
    }
    part = wave_sum(part);
  }

  if (tid == 0) wpart[wid] = part;
  __syncthreads();

  __shared__ int amLast;
  if (threadIdx.x == 0) {
    float s = 0.f;
#pragma unroll
    for (int w = 0; w < WPB; ++w) s += wpart[w];
    partial[blockIdx.x] = s;
    __threadfence();                       // release: partial visible device-wide
    const int t = atomicAdd(counter, 1);   // device-scope ticket
    amLast = (t == (int)gridDim.x - 1);
  }
  __syncthreads();

  if (amLast) {
    __threadfence();                       // acquire before reading partials
    const int nparts = gridDim.x;
    double s = 0.0;
    for (int i = threadIdx.x; i < nparts; i += BLOCK) s += (double)partial[i];
#pragma unroll
    for (int m = 32; m >= 1; m >>= 1) s += __shfl_xor(s, m);
    __shared__ double wsum[WPB];
    if (tid == 0) wsum[wid] = s;
    __syncthreads();
    if (threadIdx.x == 0) {
      double t = 0.0;
#pragma unroll
      for (int w = 0; w < WPB; ++w) t += wsum[w];
      out[0] = (float)(t / (3.0 * (double)N));
    }
  }
}

// Exclusive prefix sum of num_atoms -> starts; also resets the ticket counter.
__global__ __launch_bounds__(1024) void mdl_scan(const int* __restrict__ na,
                                                 int* __restrict__ starts, int B,
                                                 int* __restrict__ counter) {
  __shared__ int part[1024];
  const int tid = threadIdx.x;
  if (tid == 0) *counter = 0;
  const int chunk = (B + 1023) / 1024;
  const int lo = min(tid * chunk, B);
  const int hi = min(lo + chunk, B);
  int s = 0;
  if (((lo | chunk) & 3) == 0 && hi == lo + chunk) {
    const int4* na4 = (const int4*)(na + lo);
#pragma unroll 4
    for (int i = 0; i < chunk / 4; ++i) {
      const int4 v = na4[i];
      s += v.x + v.y + v.z + v.w;
    }
  } else {
    for (int i = lo; i < hi; ++i) s += na[i];
  }
  part[tid] = s;
  __syncthreads();
  for (int off = 1; off < 1024; off <<= 1) {
    int v = 0;
    if (tid >= off) v = part[tid - off];
    __syncthreads();
    if (tid >= off) part[tid] += v;
    __syncthreads();
  }
  int ex = (tid == 0) ? 0 : part[tid - 1];
  for (int i = lo; i < hi; ++i) { starts[i] = ex; ex += na[i]; }
}

extern "C" void kernel_launch(void* const* d_in, const int* in_sizes, int n_in,
                              void* d_out, int out_size, void* d_ws, size_t ws_size,
                              hipStream_t stream) {
  const float* cell = (const float*)d_in[0];
  const float* x    = (const float*)d_in[1];
  const float* xt   = (const float*)d_in[2];
  const int*   na   = (const int*)d_in[3];
  const int B = in_sizes[3];
  const int N = in_sizes[1] / 3;

  const int nblocks = (B + WPB - 1) / WPB;
  int*   counter = (int*)d_ws;                                   // 1 int (reset by scan)
  float* partial = (float*)((char*)d_ws + 256);                  // nblocks floats
  int*   starts  = (int*)((char*)d_ws + 256 +
                          (((size_t)nblocks * 4 + 255) & ~(size_t)255));

  mdl_scan<<<1, 1024, 0, stream>>>(na, starts, B, counter);
  mdl_main<<<nblocks, BLOCK, 0, stream>>>(cell, x, xt, na, starts, partial,
                                          counter, (float*)d_out, B, N);
}

// Round 5
// 36.179 us; speedup vs baseline: 3.0095x; 3.0095x over previous
//
#include <hip/hip_runtime.h>

#define WAVE 64
#define WPB 4
#define BLOCK (WAVE * WPB)
#define NBLOCKS 2048

// s = (x + OFFSETS[argmin_o |euc_xt - cell@(x+off_o)|]) - x_tilde  for atom n.
// r = cell@xt - cell@x; d_ijk = |r - i*col0 - j*col1 - k*col2|^2, expanded in k:
// |q - dk*col2|^2 = qq - 2*dk*(q.col2) + dk^2*|col2|^2.
// argmin via packed uint key: (float_bits(d) & ~31) | o  -> v_min_u32 chain,
// low-5-bit mask = tie region ~32 ulp; deviation impact << threshold.
__device__ __forceinline__ void compute_s(const float c[9], float cc2,
                                          const float* __restrict__ x,
                                          const float* __restrict__ xt,
                                          int n, float& s0, float& s1, float& s2) {
  const float x0 = x[3 * n + 0], x1 = x[3 * n + 1], x2 = x[3 * n + 2];
  const float t0 = xt[3 * n + 0], t1 = xt[3 * n + 1], t2 = xt[3 * n + 2];
  const float e0 = c[0] * t0 + c[1] * t1 + c[2] * t2;
  const float e1 = c[3] * t0 + c[4] * t1 + c[5] * t2;
  const float e2 = c[6] * t0 + c[7] * t1 + c[8] * t2;
  const float b0 = c[0] * x0 + c[1] * x1 + c[2] * x2;
  const float b1 = c[3] * x0 + c[4] * x1 + c[5] * x2;
  const float b2 = c[6] * x0 + c[7] * x1 + c[8] * x2;
  const float r0 = e0 - b0, r1 = e1 - b1, r2 = e2 - b2;

  unsigned best = 0xFFFFFFFFu;
#pragma unroll
  for (int i = 0; i < 3; ++i) {
    const float di = (float)(i - 1);
    const float p0 = r0 - di * c[0], p1 = r1 - di * c[3], p2 = r2 - di * c[6];
#pragma unroll
    for (int j = 0; j < 3; ++j) {
      const float dj = (float)(j - 1);
      const float q0 = p0 - dj * c[1], q1 = p1 - dj * c[4], q2 = p2 - dj * c[7];
      const float qq = q0 * q0 + q1 * q1 + q2 * q2;
      const float qc = q0 * c[2] + q1 * c[5] + q2 * c[8];
      const float tmp = qq + cc2;
      const float dm = fmaxf(tmp + 2.0f * qc, 0.0f);  // k=-1 (clamp cancellation)
      const float dp = fmaxf(tmp - 2.0f * qc, 0.0f);  // k=+1
      const unsigned ob = (unsigned)(9 * i + 3 * j);
      const unsigned km = (__float_as_uint(dm) & ~31u) | (ob + 0u);
      const unsigned k0 = (__float_as_uint(qq) & ~31u) | (ob + 1u);
      const unsigned kp = (__float_as_uint(dp) & ~31u) | (ob + 2u);
      best = min(best, min(km, min(k0, kp)));
    }
  }
  const int o = (int)(best & 31u);
  s0 = x0 + (float)(o / 9 - 1) - t0;
  s1 = x1 + (float)((o / 3) % 3 - 1) - t1;
  s2 = x2 + (float)(o % 3 - 1) - t2;
}

__device__ __forceinline__ float wave_sum(float v) {
#pragma unroll
  for (int m = 32; m >= 1; m >>= 1) v += __shfl_xor(v, m);
  return v;
}

// Grid-stride over structures: one structure per wave per iteration.
// Per-wave |.| partial accumulates in registers; one block partial, NO atomics.
__global__ __launch_bounds__(BLOCK) void mdl_main(const float* __restrict__ cell,
                                                  const float* __restrict__ x,
                                                  const float* __restrict__ xt,
                                                  const int* __restrict__ na,
                                                  const int* __restrict__ starts,
                                                  float* __restrict__ partial, int B) {
  __shared__ float wpart[WPB];
  const int wid = __builtin_amdgcn_readfirstlane(threadIdx.x / WAVE);
  const int tid = threadIdx.x % WAVE;
  const int W = gridDim.x * WPB;  // total waves

  float part = 0.f;
  for (int b = blockIdx.x * WPB + wid; b < B; b += W) {
    const int start = starts[b];
    const int count = na[b];

    float c[9];
#pragma unroll
    for (int i = 0; i < 9; ++i) c[i] = cell[9 * b + i];
    const float cc2 = c[2] * c[2] + c[5] * c[5] + c[8] * c[8];

    float sumx = 0.f, sumy = 0.f, sumz = 0.f;
    float s0 = 0.f, s1 = 0.f, s2 = 0.f;
    bool have = false;

    if (count <= WAVE) {
      if (tid < count) {
        compute_s(c, cc2, x, xt, start + tid, s0, s1, s2);
        have = true;
        sumx = s0; sumy = s1; sumz = s2;
      }
    } else {
      for (int n = start + tid; n < start + count; n += WAVE) {
        float a0, a1, a2;
        compute_s(c, cc2, x, xt, n, a0, a1, a2);
        sumx += a0; sumy += a1; sumz += a2;
      }
    }

    sumx = wave_sum(sumx); sumy = wave_sum(sumy); sumz = wave_sum(sumz);
    const float inv = 1.0f / (float)count;
    const float cx = sumx * inv, cy = sumy * inv, cz = sumz * inv;

    if (count <= WAVE) {
      if (have) part += fabsf(cx - s0) + fabsf(cy - s1) + fabsf(cz - s2);
    } else {
      for (int n = start + tid; n < start + count; n += WAVE) {
        float a0, a1, a2;
        compute_s(c, cc2, x, xt, n, a0, a1, a2);
        part += fabsf(cx - a0) + fabsf(cy - a1) + fabsf(cz - a2);
      }
    }
  }

  part = wave_sum(part);
  if (tid == 0) wpart[wid] = part;
  __syncthreads();
  if (threadIdx.x == 0) {
    float s = 0.f;
#pragma unroll
    for (int w = 0; w < WPB; ++w) s += wpart[w];
    partial[blockIdx.x] = s;
  }
}

// Exclusive prefix sum of num_atoms -> starts[0..B-1].
__global__ __launch_bounds__(1024) void mdl_scan(const int* __restrict__ na,
                                                 int* __restrict__ starts, int B) {
  __shared__ int part[1024];
  const int tid = threadIdx.x;
  const int chunk = (B + 1023) / 1024;
  const int lo = min(tid * chunk, B);
  const int hi = min(lo + chunk, B);
  int s = 0;
  if (((lo | chunk) & 3) == 0 && hi == lo + chunk) {
    const int4* na4 = (const int4*)(na + lo);
#pragma unroll 4
    for (int i = 0; i < chunk / 4; ++i) {
      const int4 v = na4[i];
      s += v.x + v.y + v.z + v.w;
    }
  } else {
    for (int i = lo; i < hi; ++i) s += na[i];
  }
  part[tid] = s;
  __syncthreads();
  for (int off = 1; off < 1024; off <<= 1) {
    int v = 0;
    if (tid >= off) v = part[tid - off];
    __syncthreads();
    if (tid >= off) part[tid] += v;
    __syncthreads();
  }
  int ex = (tid == 0) ? 0 : part[tid - 1];
  for (int i = lo; i < hi; ++i) { starts[i] = ex; ex += na[i]; }
}

// Sum nparts floats (double accum) -> out = sum / (3*N).
__global__ __launch_bounds__(256) void mdl_final(const float* __restrict__ partial,
                                                 int nparts, float* __restrict__ out,
                                                 int N) {
  __shared__ double wsum[4];
  double s = 0.0;
  for (int i = threadIdx.x; i < nparts; i += 256) s += (double)partial[i];
#pragma unroll
  for (int m = 32; m >= 1; m >>= 1) s += __shfl_xor(s, m);
  if ((threadIdx.x & (WAVE - 1)) == 0) wsum[threadIdx.x / WAVE] = s;
  __syncthreads();
  if (threadIdx.x == 0) {
    double t = 0.0;
#pragma unroll
    for (int w = 0; w < 4; ++w) t += wsum[w];
    out[0] = (float)(t / (3.0 * (double)N));
  }
}

extern "C" void kernel_launch(void* const* d_in, const int* in_sizes, int n_in,
                              void* d_out, int out_size, void* d_ws, size_t ws_size,
                              hipStream_t stream) {
  const float* cell = (const float*)d_in[0];
  const float* x    = (const float*)d_in[1];
  const float* xt   = (const float*)d_in[2];
  const int*   na   = (const int*)d_in[3];
  const int B = in_sizes[3];
  const int N = in_sizes[1] / 3;

  int nblocks = (B + WPB - 1) / WPB;
  if (nblocks > NBLOCKS) nblocks = NBLOCKS;
  float* partial = (float*)d_ws;                              // nblocks floats
  int* starts = (int*)((char*)d_ws + (((size_t)nblocks * 4 + 255) & ~(size_t)255));

  mdl_scan<<<1, 1024, 0, stream>>>(na, starts, B);
  mdl_main<<<nblocks, BLOCK, 0, stream>>>(cell, x, xt, na, starts, partial, B);
  mdl_final<<<1, 256, 0, stream>>>(partial, nblocks, (float*)d_out, N);
}

// Round 6
// 22.985 us; speedup vs baseline: 4.7371x; 1.5741x over previous
//
#include <hip/hip_runtime.h>

#define WAVE 64
#define WPB 4
#define BLOCK (WAVE * WPB)
#define NBLOCKS 2048

// argmin over 27 periodic images given preloaded coords; s = x + off[o] - t.
// r = cell@t - cell@x; d_ijk = |r - i*col0 - j*col1 - k*col2|^2, expanded in k:
// |q - dk*col2|^2 = qq -+ 2*(q.col2) + cc2.  Packed uint key (bits&~31)|o ->
// v_min3_u32 chains; low-5-bit tie region ~32ulp << 7.9e-4 threshold.
__device__ __forceinline__ void argmin_s(const float c[9], float cc2,
                                         float x0, float x1, float x2,
                                         float t0, float t1, float t2,
                                         float& s0, float& s1, float& s2) {
  const float e0 = c[0] * t0 + c[1] * t1 + c[2] * t2;
  const float e1 = c[3] * t0 + c[4] * t1 + c[5] * t2;
  const float e2 = c[6] * t0 + c[7] * t1 + c[8] * t2;
  const float b0 = c[0] * x0 + c[1] * x1 + c[2] * x2;
  const float b1 = c[3] * x0 + c[4] * x1 + c[5] * x2;
  const float b2 = c[6] * x0 + c[7] * x1 + c[8] * x2;
  const float r0 = e0 - b0, r1 = e1 - b1, r2 = e2 - b2;

  unsigned best = 0xFFFFFFFFu;
#pragma unroll
  for (int i = 0; i < 3; ++i) {
    const float di = (float)(i - 1);
    const float p0 = r0 - di * c[0], p1 = r1 - di * c[3], p2 = r2 - di * c[6];
#pragma unroll
    for (int j = 0; j < 3; ++j) {
      const float dj = (float)(j - 1);
      const float q0 = p0 - dj * c[1], q1 = p1 - dj * c[4], q2 = p2 - dj * c[7];
      const float qq = q0 * q0 + q1 * q1 + q2 * q2;
      const float qc = q0 * c[2] + q1 * c[5] + q2 * c[8];
      const float tmp = qq + cc2;
      const float dm = fmaxf(tmp + 2.0f * qc, 0.0f);  // k=-1
      const float dp = fmaxf(tmp - 2.0f * qc, 0.0f);  // k=+1
      const unsigned ob = (unsigned)(9 * i + 3 * j);
      const unsigned km = (__float_as_uint(dm) & ~31u) | (ob + 0u);
      const unsigned k0 = (__float_as_uint(qq) & ~31u) | (ob + 1u);
      const unsigned kp = (__float_as_uint(dp) & ~31u) | (ob + 2u);
      best = min(best, min(km, min(k0, kp)));
    }
  }
  const int o = (int)(best & 31u);
  s0 = x0 + (float)(o / 9 - 1) - t0;
  s1 = x1 + (float)((o / 3) % 3 - 1) - t1;
  s2 = x2 + (float)(o % 3 - 1) - t2;
}

__device__ __forceinline__ float wave_sum(float v) {
#pragma unroll
  for (int m = 32; m >= 1; m >>= 1) v += __shfl_xor(v, m);
  return v;
}

// One structure, coords already in registers (count <= WAVE fast path).
__device__ __forceinline__ float structure_fast(const float c[9], float cc2,
                                                bool have, int count,
                                                float x0, float x1, float x2,
                                                float t0, float t1, float t2) {
  float s0 = 0.f, s1 = 0.f, s2 = 0.f;
  if (have) argmin_s(c, cc2, x0, x1, x2, t0, t1, t2, s0, s1, s2);
  const float sx = wave_sum(s0), sy = wave_sum(s1), sz = wave_sum(s2);
  const float inv = 1.0f / (float)count;
  const float cx = sx * inv, cy = sy * inv, cz = sz * inv;
  return have ? (fabsf(cx - s0) + fabsf(cy - s1) + fabsf(cz - s2)) : 0.f;
}

// General path (count > WAVE): stream atoms, recompute s for |.| pass.
__device__ __forceinline__ float structure_general(const float c[9], float cc2,
                                                   const float* __restrict__ x,
                                                   const float* __restrict__ xt,
                                                   int start, int count, int tid) {
  float sumx = 0.f, sumy = 0.f, sumz = 0.f;
  for (int n = start + tid; n < start + count; n += WAVE) {
    float a0, a1, a2;
    argmin_s(c, cc2, x[3 * n], x[3 * n + 1], x[3 * n + 2],
             xt[3 * n], xt[3 * n + 1], xt[3 * n + 2], a0, a1, a2);
    sumx += a0; sumy += a1; sumz += a2;
  }
  sumx = wave_sum(sumx); sumy = wave_sum(sumy); sumz = wave_sum(sumz);
  const float inv = 1.0f / (float)count;
  const float cx = sumx * inv, cy = sumy * inv, cz = sumz * inv;
  float part = 0.f;
  for (int n = start + tid; n < start + count; n += WAVE) {
    float a0, a1, a2;
    argmin_s(c, cc2, x[3 * n], x[3 * n + 1], x[3 * n + 2],
             xt[3 * n], xt[3 * n + 1], xt[3 * n + 2], a0, a1, a2);
    part += fabsf(cx - a0) + fabsf(cy - a1) + fabsf(cz - a2);
  }
  return part;
}

// 4 waves/block; each wave handles a PAIR of structures (b, b+W) per loop iter,
// with all global loads for both issued before any compute (latency overlap).
__global__ __launch_bounds__(BLOCK) void mdl_main(const float* __restrict__ cell,
                                                  const float* __restrict__ x,
                                                  const float* __restrict__ xt,
                                                  const int* __restrict__ na,
                                                  const int* __restrict__ starts,
                                                  float* __restrict__ partial, int B) {
  __shared__ float wpart[WPB];
  const int wid = threadIdx.x / WAVE;
  const int tid = threadIdx.x % WAVE;
  const int W = gridDim.x * WPB;

  float part = 0.f;
  for (int b = __builtin_amdgcn_readfirstlane(blockIdx.x * WPB + wid); b < B;
       b += 2 * W) {
    const int bA = b;
    const int bB = b + W;
    const bool hasB = (bB < B);

    const int startA = starts[bA];
    const int countA = na[bA];
    int startB = 0, countB = 0;
    if (hasB) { startB = starts[bB]; countB = na[bB]; }

    float cA[9], cB[9];
#pragma unroll
    for (int i = 0; i < 9; ++i) cA[i] = cell[9 * bA + i];
    if (hasB) {
#pragma unroll
      for (int i = 0; i < 9; ++i) cB[i] = cell[9 * bB + i];
    }
    const float ccA = cA[2] * cA[2] + cA[5] * cA[5] + cA[8] * cA[8];
    const float ccB = hasB ? (cB[2] * cB[2] + cB[5] * cB[5] + cB[8] * cB[8]) : 0.f;

    if (countA <= WAVE && (!hasB || countB <= WAVE)) {
      // ---- fast dual path: issue ALL loads up front, then compute ----
      const bool haveA = tid < countA;
      const bool haveB = hasB && tid < countB;
      float xA0 = 0, xA1 = 0, xA2 = 0, tA0 = 0, tA1 = 0, tA2 = 0;
      float xB0 = 0, xB1 = 0, xB2 = 0, tB0 = 0, tB1 = 0, tB2 = 0;
      if (haveA) {
        const int n = startA + tid;
        xA0 = x[3 * n]; xA1 = x[3 * n + 1]; xA2 = x[3 * n + 2];
        tA0 = xt[3 * n]; tA1 = xt[3 * n + 1]; tA2 = xt[3 * n + 2];
      }
      if (haveB) {
        const int n = startB + tid;
        xB0 = x[3 * n]; xB1 = x[3 * n + 1]; xB2 = x[3 * n + 2];
        tB0 = xt[3 * n]; tB1 = xt[3 * n + 1]; tB2 = xt[3 * n + 2];
      }
      part += structure_fast(cA, ccA, haveA, countA, xA0, xA1, xA2, tA0, tA1, tA2);
      if (hasB)
        part += structure_fast(cB, ccB, haveB, countB, xB0, xB1, xB2, tB0, tB1, tB2);
    } else {
      part += structure_general(cA, ccA, x, xt, startA, countA, tid);
      if (hasB) part += structure_general(cB, ccB, x, xt, startB, countB, tid);
    }
  }

  part = wave_sum(part);
  if (tid == 0) wpart[wid] = part;
  __syncthreads();
  if (threadIdx.x == 0) {
    float s = 0.f;
#pragma unroll
    for (int w = 0; w < WPB; ++w) s += wpart[w];
    partial[blockIdx.x] = s;
  }
}

// Exclusive prefix sum of num_atoms -> starts. Fast path: 16 ints/thread in
// registers + __shfl_up wave scan, only 2 barriers. Fallback: Hillis-Steele.
__global__ __launch_bounds__(1024) void mdl_scan(const int* __restrict__ na,
                                                 int* __restrict__ starts, int B) {
  const int t = threadIdx.x;
  if ((B & 15) == 0 && B <= 16 * 1024) {
    const int active = B >> 4;
    __shared__ int wtot[16];
    int v[16];
    int tot = 0;
    if (t < active) {
      const int4* p = (const int4*)(na + t * 16);
#pragma unroll
      for (int i = 0; i < 4; ++i) {
        const int4 q = p[i];
        v[4 * i + 0] = q.x; v[4 * i + 1] = q.y; v[4 * i + 2] = q.z; v[4 * i + 3] = q.w;
      }
#pragma unroll
      for (int i = 0; i < 16; ++i) tot += v[i];
    } else {
#pragma unroll
      for (int i = 0; i < 16; ++i) v[i] = 0;
    }
    // inclusive wave scan of per-thread totals
    int sc = tot;
#pragma unroll
    for (int m = 1; m < 64; m <<= 1) {
      const int u = __shfl_up(sc, m);
      if ((t & 63) >= m) sc += u;
    }
    if ((t & 63) == 63) wtot[t >> 6] = sc;
    __syncthreads();
    if (t == 0) {
      int acc = 0;
#pragma unroll
      for (int w = 0; w < 16; ++w) { const int q = wtot[w]; wtot[w] = acc; acc += q; }
    }
    __syncthreads();
    if (t < active) {
      int ex = wtot[t >> 6] + (sc - tot);  // exclusive prefix of this thread's chunk
      int out[16];
#pragma unroll
      for (int i = 0; i < 16; ++i) { out[i] = ex; ex += v[i]; }
      int4* q = (int4*)(starts + t * 16);
#pragma unroll
      for (int i = 0; i < 4; ++i)
        q[i] = make_int4(out[4 * i], out[4 * i + 1], out[4 * i + 2], out[4 * i + 3]);
    }
  } else {
    __shared__ int part[1024];
    const int chunk = (B + 1023) / 1024;
    const int lo = min(t * chunk, B);
    const int hi = min(lo + chunk, B);
    int s = 0;
    for (int i = lo; i < hi; ++i) s += na[i];
    part[t] = s;
    __syncthreads();
    for (int off = 1; off < 1024; off <<= 1) {
      int v2 = 0;
      if (t >= off) v2 = part[t - off];
      __syncthreads();
      if (t >= off) part[t] += v2;
      __syncthreads();
    }
    int ex = (t == 0) ? 0 : part[t - 1];
    for (int i = lo; i < hi; ++i) { starts[i] = ex; ex += na[i]; }
  }
}

// Sum nparts floats (double accum) -> out = sum / (3*N).
__global__ __launch_bounds__(256) void mdl_final(const float* __restrict__ partial,
                                                 int nparts, float* __restrict__ out,
                                                 int N) {
  __shared__ double wsum[4];
  double s = 0.0;
  for (int i = threadIdx.x; i < nparts; i += 256) s += (double)partial[i];
#pragma unroll
  for (int m = 32; m >= 1; m >>= 1) s += __shfl_xor(s, m);
  if ((threadIdx.x & (WAVE - 1)) == 0) wsum[threadIdx.x / WAVE] = s;
  __syncthreads();
  if (threadIdx.x == 0) {
    double t = 0.0;
#pragma unroll
    for (int w = 0; w < 4; ++w) t += wsum[w];
    out[0] = (float)(t / (3.0 * (double)N));
  }
}

extern "C" void kernel_launch(void* const* d_in, const int* in_sizes, int n_in,
                              void* d_out, int out_size, void* d_ws, size_t ws_size,
                              hipStream_t stream) {
  const float* cell = (const float*)d_in[0];
  const float* x    = (const float*)d_in[1];
  const float* xt   = (const float*)d_in[2];
  const int*   na   = (const int*)d_in[3];
  const int B = in_sizes[3];
  const int N = in_sizes[1] / 3;

  int nblocks = (B + WPB - 1) / WPB;
  if (nblocks > NBLOCKS) nblocks = NBLOCKS;
  float* partial = (float*)d_ws;  // nblocks floats
  int* starts = (int*)((char*)d_ws + (((size_t)nblocks * 4 + 255) & ~(size_t)255));

  mdl_scan<<<1, 1024, 0, stream>>>(na, starts, B);
  mdl_main<<<nblocks, BLOCK, 0, stream>>>(cell, x, xt, na, starts, partial, B);
  mdl_final<<<1, 256, 0, stream>>>(partial, nblocks, (float*)d_out, N);
}

// Round 8
// 17.983 us; speedup vs baseline: 6.0545x; 1.2781x over previous
//
#include <hip/hip_runtime.h>

#define WAVE 64
#define WPB 4                 // waves per block
#define SPB (2 * WPB)         // structures per block (2 per wave, consecutive)
#define BLOCK (WAVE * WPB)

// argmin over 27 periodic images given preloaded coords; s = x + off[o] - t.
// r = cell@t - cell@x; d_ijk = |r - i*col0 - j*col1 - k*col2|^2, expanded in k:
// |q - dk*col2|^2 = qq -+ 2*(q.col2) + cc2.  Packed uint key (bits&~31)|o ->
// v_min_u32 chains; low-5-bit tie region ~32ulp << 7.9e-4 threshold.
__device__ __forceinline__ void argmin_s(const float c[9], float cc2,
                                         float x0, float x1, float x2,
                                         float t0, float t1, float t2,
                                         float& s0, float& s1, float& s2) {
  const float e0 = c[0] * t0 + c[1] * t1 + c[2] * t2;
  const float e1 = c[3] * t0 + c[4] * t1 + c[5] * t2;
  const float e2 = c[6] * t0 + c[7] * t1 + c[8] * t2;
  const float b0 = c[0] * x0 + c[1] * x1 + c[2] * x2;
  const float b1 = c[3] * x0 + c[4] * x1 + c[5] * x2;
  const float b2 = c[6] * x0 + c[7] * x1 + c[8] * x2;
  const float r0 = e0 - b0, r1 = e1 - b1, r2 = e2 - b2;

  unsigned best = 0xFFFFFFFFu;
#pragma unroll
  for (int i = 0; i < 3; ++i) {
    const float di = (float)(i - 1);
    const float p0 = r0 - di * c[0], p1 = r1 - di * c[3], p2 = r2 - di * c[6];
#pragma unroll
    for (int j = 0; j < 3; ++j) {
      const float dj = (float)(j - 1);
      const float q0 = p0 - dj * c[1], q1 = p1 - dj * c[4], q2 = p2 - dj * c[7];
      const float qq = q0 * q0 + q1 * q1 + q2 * q2;
      const float qc = q0 * c[2] + q1 * c[5] + q2 * c[8];
      const float tmp = qq + cc2;
      const float dm = fmaxf(tmp + 2.0f * qc, 0.0f);  // k=-1
      const float dp = fmaxf(tmp - 2.0f * qc, 0.0f);  // k=+1
      const unsigned ob = (unsigned)(9 * i + 3 * j);
      const unsigned km = (__float_as_uint(dm) & ~31u) | (ob + 0u);
      const unsigned k0 = (__float_as_uint(qq) & ~31u) | (ob + 1u);
      const unsigned kp = (__float_as_uint(dp) & ~31u) | (ob + 2u);
      best = min(best, min(km, min(k0, kp)));
    }
  }
  const int o = (int)(best & 31u);
  s0 = x0 + (float)(o / 9 - 1) - t0;
  s1 = x1 + (float)((o / 3) % 3 - 1) - t1;
  s2 = x2 + (float)(o % 3 - 1) - t2;
}

__device__ __forceinline__ float wave_sum(float v) {
#pragma unroll
  for (int m = 32; m >= 1; m >>= 1) v += __shfl_xor(v, m);
  return v;
}

__device__ __forceinline__ int wave_sum_i(int v) {
#pragma unroll
  for (int m = 32; m >= 1; m >>= 1) v += __shfl_xor(v, m);
  return v;
}

// One structure, coords already in registers (count <= WAVE fast path).
__device__ __forceinline__ float structure_fast(const float c[9], float cc2,
                                                bool have, int count,
                                                float x0, float x1, float x2,
                                                float t0, float t1, float t2) {
  float s0 = 0.f, s1 = 0.f, s2 = 0.f;
  if (have) argmin_s(c, cc2, x0, x1, x2, t0, t1, t2, s0, s1, s2);
  const float sx = wave_sum(s0), sy = wave_sum(s1), sz = wave_sum(s2);
  const float inv = 1.0f / (float)count;
  const float cx = sx * inv, cy = sy * inv, cz = sz * inv;
  return have ? (fabsf(cx - s0) + fabsf(cy - s1) + fabsf(cz - s2)) : 0.f;
}

// General path (count > WAVE): stream atoms, recompute s for |.| pass.
__device__ __forceinline__ float structure_general(const float c[9], float cc2,
                                                   const float* __restrict__ x,
                                                   const float* __restrict__ xt,
                                                   int start, int count, int tid) {
  float sumx = 0.f, sumy = 0.f, sumz = 0.f;
  for (int n = start + tid; n < start + count; n += WAVE) {
    float a0, a1, a2;
    argmin_s(c, cc2, x[3 * n], x[3 * n + 1], x[3 * n + 2],
             xt[3 * n], xt[3 * n + 1], xt[3 * n + 2], a0, a1, a2);
    sumx += a0; sumy += a1; sumz += a2;
  }
  sumx = wave_sum(sumx); sumy = wave_sum(sumy); sumz = wave_sum(sumz);
  const float inv = 1.0f / (float)count;
  const float cx = sumx * inv, cy = sumy * inv, cz = sumz * inv;
  float part = 0.f;
  for (int n = start + tid; n < start + count; n += WAVE) {
    float a0, a1, a2;
    argmin_s(c, cc2, x[3 * n], x[3 * n + 1], x[3 * n + 2],
             xt[3 * n], xt[3 * n + 1], xt[3 * n + 2], a0, a1, a2);
    part += fabsf(cx - a0) + fabsf(cy - a1) + fabsf(cz - a2);
  }
  return part;
}

// Fused kernel: block owns 8 consecutive structures. Prologue computes
// base = sum(na[0..8*blk)) cooperatively (na is 64KB -> L2-resident), then an
// 8-lane shfl scan gives per-wave start/count. No separate scan kernel, no
// starts[] array. Each wave handles structures (2w, 2w+1): adjacent -> its 12
// coord loads cover one contiguous ~3KB region.
__global__ __launch_bounds__(BLOCK) void mdl_main(const float* __restrict__ cell,
                                                  const float* __restrict__ x,
                                                  const float* __restrict__ xt,
                                                  const int* __restrict__ na,
                                                  float* __restrict__ partial, int B) {
  __shared__ int ired[WPB];
  __shared__ float wpart[WPB];
  const int wid = __builtin_amdgcn_readfirstlane(threadIdx.x / WAVE);
  const int tid = threadIdx.x % WAVE;
  const int blk8 = blockIdx.x * SPB;  // always multiple of 8

  // ---- fused exclusive-prefix: base = sum(na[0..blk8)) ----
  int s = 0;
  const int nv = blk8 >> 2;  // exact: blk8 % 4 == 0
  const int4* na4 = (const int4*)na;
  for (int v = threadIdx.x; v < nv; v += BLOCK) {
    const int4 q = na4[v];
    s += q.x + q.y + q.z + q.w;
  }
  s = wave_sum_i(s);
  if (tid == 0) ired[wid] = s;

  // per-wave: the block's 8 structure sizes + 8-lane inclusive scan
  int nloc = 0;
  if (tid < SPB && blk8 + tid < B) nloc = na[blk8 + tid];
  int inc = nloc;
#pragma unroll
  for (int m = 1; m < SPB; m <<= 1) {
    const int u = __shfl_up(inc, m);
    if (tid >= m) inc += u;  // lanes >= 8 hold garbage, never read
  }
  __syncthreads();
  const int base = ired[0] + ired[1] + ired[2] + ired[3];

  const int laneA = 2 * wid, laneB = laneA + 1;
  const int nA = __shfl(nloc, laneA), incA = __shfl(inc, laneA);
  const int nB = __shfl(nloc, laneB), incB = __shfl(inc, laneB);
  const int startA = __builtin_amdgcn_readfirstlane(base + incA - nA);
  const int countA = __builtin_amdgcn_readfirstlane(nA);
  const int startB = __builtin_amdgcn_readfirstlane(base + incB - nB);
  const int countB = __builtin_amdgcn_readfirstlane(nB);
  const int bA = blk8 + laneA;
  const int bB = blk8 + laneB;
  const bool hasA = bA < B;
  const bool hasB = bB < B;

  float part = 0.f;
  if (hasA) {
    float cA[9];
#pragma unroll
    for (int i = 0; i < 9; ++i) cA[i] = cell[9 * bA + i];
    const float ccA = cA[2] * cA[2] + cA[5] * cA[5] + cA[8] * cA[8];
    float cB[9] = {0, 0, 0, 0, 0, 0, 0, 0, 0};
    float ccB = 0.f;
    if (hasB) {
#pragma unroll
      for (int i = 0; i < 9; ++i) cB[i] = cell[9 * bB + i];
      ccB = cB[2] * cB[2] + cB[5] * cB[5] + cB[8] * cB[8];
    }

    if (countA <= WAVE && (!hasB || countB <= WAVE)) {
      // fast dual path: issue ALL coord loads up front, then compute
      const bool haveA = tid < countA;
      const bool haveB = hasB && tid < countB;
      float xA0 = 0, xA1 = 0, xA2 = 0, tA0 = 0, tA1 = 0, tA2 = 0;
      float xB0 = 0, xB1 = 0, xB2 = 0, tB0 = 0, tB1 = 0, tB2 = 0;
      if (haveA) {
        const int n = startA + tid;
        xA0 = x[3 * n]; xA1 = x[3 * n + 1]; xA2 = x[3 * n + 2];
        tA0 = xt[3 * n]; tA1 = xt[3 * n + 1]; tA2 = xt[3 * n + 2];
      }
      if (haveB) {
        const int n = startB + tid;
        xB0 = x[3 * n]; xB1 = x[3 * n + 1]; xB2 = x[3 * n + 2];
        tB0 = xt[3 * n]; tB1 = xt[3 * n + 1]; tB2 = xt[3 * n + 2];
      }
      part += structure_fast(cA, ccA, haveA, countA, xA0, xA1, xA2, tA0, tA1, tA2);
      if (hasB)
        part += structure_fast(cB, ccB, haveB, countB, xB0, xB1, xB2, tB0, tB1, tB2);
    } else {
      part += structure_general(cA, ccA, x, xt, startA, countA, tid);
      if (hasB) part += structure_general(cB, ccB, x, xt, startB, countB, tid);
    }
  }

  part = wave_sum(part);
  if (tid == 0) wpart[wid] = part;
  __syncthreads();
  if (threadIdx.x == 0)
    partial[blockIdx.x] = wpart[0] + wpart[1] + wpart[2] + wpart[3];
}

// Sum nparts floats (double accum) -> out = sum / (3*N).
__global__ __launch_bounds__(256) void mdl_final(const float* __restrict__ partial,
                                                 int nparts, float* __restrict__ out,
                                                 int N) {
  __shared__ double wsum[4];
  double s = 0.0;
  for (int i = threadIdx.x; i < nparts; i += 256) s += (double)partial[i];
#pragma unroll
  for (int m = 32; m >= 1; m >>= 1) s += __shfl_xor(s, m);
  if ((threadIdx.x & (WAVE - 1)) == 0) wsum[threadIdx.x / WAVE] = s;
  __syncthreads();
  if (threadIdx.x == 0) {
    double t = 0.0;
#pragma unroll
    for (int w = 0; w < 4; ++w) t += wsum[w];
    out[0] = (float)(t / (3.0 * (double)N));
  }
}

extern "C" void kernel_launch(void* const* d_in, const int* in_sizes, int n_in,
                              void* d_out, int out_size, void* d_ws, size_t ws_size,
                              hipStream_t stream) {
  const float* cell = (const float*)d_in[0];
  const float* x    = (const float*)d_in[1];
  const float* xt   = (const float*)d_in[2];
  const int*   na   = (const int*)d_in[3];
  const int B = in_sizes[3];
  const int N = in_sizes[1] / 3;

  const int nblocks = (B + SPB - 1) / SPB;
  float* partial = (float*)d_ws;  // nblocks floats

  mdl_main<<<nblocks, BLOCK, 0, stream>>>(cell, x, xt, na, partial, B);
  mdl_final<<<1, 256, 0, stream>>>(partial, nblocks, (float*)d_out, N);
}

// Round 10
// 17.837 us; speedup vs baseline: 6.1040x; 1.0082x over previous
//
#include <hip/hip_runtime.h>

#define WAVE 64
#define WPB 8                 // waves per block
#define SPB (2 * WPB)         // structures per block (2 per wave, consecutive)
#define BLOCK (WAVE * WPB)    // 512

// argmin over 27 periodic images given preloaded coords; s = x + off[o] - t.
// r = cell@t - cell@x; d_ijk = |r - i*col0 - j*col1 - k*col2|^2, expanded in k:
// |q - dk*col2|^2 = qq -+ 2*(q.col2) + cc2.  Packed uint key (bits&~31)|o ->
// v_min_u32 chains; low-5-bit tie region ~32ulp << 7.9e-4 threshold.
__device__ __forceinline__ void argmin_s(const float c[9], float cc2,
                                         float x0, float x1, float x2,
                                         float t0, float t1, float t2,
                                         float& s0, float& s1, float& s2) {
  const float e0 = c[0] * t0 + c[1] * t1 + c[2] * t2;
  const float e1 = c[3] * t0 + c[4] * t1 + c[5] * t2;
  const float e2 = c[6] * t0 + c[7] * t1 + c[8] * t2;
  const float b0 = c[0] * x0 + c[1] * x1 + c[2] * x2;
  const float b1 = c[3] * x0 + c[4] * x1 + c[5] * x2;
  const float b2 = c[6] * x0 + c[7] * x1 + c[8] * x2;
  const float r0 = e0 - b0, r1 = e1 - b1, r2 = e2 - b2;

  unsigned best = 0xFFFFFFFFu;
#pragma unroll
  for (int i = 0; i < 3; ++i) {
    const float di = (float)(i - 1);
    const float p0 = r0 - di * c[0], p1 = r1 - di * c[3], p2 = r2 - di * c[6];
#pragma unroll
    for (int j = 0; j < 3; ++j) {
      const float dj = (float)(j - 1);
      const float q0 = p0 - dj * c[1], q1 = p1 - dj * c[4], q2 = p2 - dj * c[7];
      const float qq = q0 * q0 + q1 * q1 + q2 * q2;
      const float qc = q0 * c[2] + q1 * c[5] + q2 * c[8];
      const float tmp = qq + cc2;
      const float dm = fmaxf(tmp + 2.0f * qc, 0.0f);  // k=-1
      const float dp = fmaxf(tmp - 2.0f * qc, 0.0f);  // k=+1
      const unsigned ob = (unsigned)(9 * i + 3 * j);
      const unsigned km = (__float_as_uint(dm) & ~31u) | (ob + 0u);
      const unsigned k0 = (__float_as_uint(qq) & ~31u) | (ob + 1u);
      const unsigned kp = (__float_as_uint(dp) & ~31u) | (ob + 2u);
      best = min(best, min(km, min(k0, kp)));
    }
  }
  const int o = (int)(best & 31u);
  s0 = x0 + (float)(o / 9 - 1) - t0;
  s1 = x1 + (float)((o / 3) % 3 - 1) - t1;
  s2 = x2 + (float)(o % 3 - 1) - t2;
}

__device__ __forceinline__ float wave_sum(float v) {
#pragma unroll
  for (int m = 32; m >= 1; m >>= 1) v += __shfl_xor(v, m);
  return v;
}

__device__ __forceinline__ int wave_sum_i(int v) {
#pragma unroll
  for (int m = 32; m >= 1; m >>= 1) v += __shfl_xor(v, m);
  return v;
}

// One structure, coords already in registers (count <= WAVE fast path).
__device__ __forceinline__ float structure_fast(const float c[9], float cc2,
                                                bool have, int count,
                                                float x0, float x1, float x2,
                                                float t0, float t1, float t2) {
  float s0 = 0.f, s1 = 0.f, s2 = 0.f;
  if (have) argmin_s(c, cc2, x0, x1, x2, t0, t1, t2, s0, s1, s2);
  const float sx = wave_sum(s0), sy = wave_sum(s1), sz = wave_sum(s2);
  const float inv = 1.0f / (float)count;
  const float cx = sx * inv, cy = sy * inv, cz = sz * inv;
  return have ? (fabsf(cx - s0) + fabsf(cy - s1) + fabsf(cz - s2)) : 0.f;
}

// General path (any count): stream atoms, recompute s for |.| pass.
__device__ __forceinline__ float structure_general(const float c[9], float cc2,
                                                   const float* __restrict__ x,
                                                   const float* __restrict__ xt,
                                                   int start, int count, int tid) {
  float sumx = 0.f, sumy = 0.f, sumz = 0.f;
  for (int n = start + tid; n < start + count; n += WAVE) {
    float a0, a1, a2;
    argmin_s(c, cc2, x[3 * n], x[3 * n + 1], x[3 * n + 2],
             xt[3 * n], xt[3 * n + 1], xt[3 * n + 2], a0, a1, a2);
    sumx += a0; sumy += a1; sumz += a2;
  }
  sumx = wave_sum(sumx); sumy = wave_sum(sumy); sumz = wave_sum(sumz);
  const float inv = 1.0f / (float)count;
  const float cx = sumx * inv, cy = sumy * inv, cz = sumz * inv;
  float part = 0.f;
  for (int n = start + tid; n < start + count; n += WAVE) {
    float a0, a1, a2;
    argmin_s(c, cc2, x[3 * n], x[3 * n + 1], x[3 * n + 2],
             xt[3 * n], xt[3 * n + 1], xt[3 * n + 2], a0, a1, a2);
    part += fabsf(cx - a0) + fabsf(cy - a1) + fabsf(cz - a2);
  }
  return part;
}

// Fused kernel, speculative-prefetch version. Block owns 16 consecutive
// structures (2 per wave). Coord loads are issued IMMEDIATELY with addresses
// predicted from na[0] (uniform-count hypothesis), overlapping the triangular
// prefix-sum; the actual scan then verifies start/count per wave (scalar
// compare) and falls back to a reload path on mismatch.
__global__ __launch_bounds__(BLOCK) void mdl_main(const float* __restrict__ cell,
                                                  const float* __restrict__ x,
                                                  const float* __restrict__ xt,
                                                  const int* __restrict__ na,
                                                  float* __restrict__ partial,
                                                  int B, int N) {
  __shared__ int ired[WPB];
  __shared__ float wpart[WPB];
  const int wid = __builtin_amdgcn_readfirstlane(threadIdx.x / WAVE);
  const int tid = threadIdx.x % WAVE;
  const int blk = blockIdx.x * SPB;  // multiple of 16

  const int bA = blk + 2 * wid;
  const int bB = bA + 1;
  const bool hasA = bA < B;
  const bool hasB = bB < B;

  // uniform-count speculation setup (all scalar)
  const int na0 = __builtin_amdgcn_readfirstlane(na[0]);
  const bool spec = (na0 > 0) && (na0 <= WAVE) &&
                    ((long)(blk + SPB) * (long)na0 <= (long)N);

  // ---- speculative coord prefetch + cell loads (issued before the scan) ----
  float xA0 = 0, xA1 = 0, xA2 = 0, tA0 = 0, tA1 = 0, tA2 = 0;
  float xB0 = 0, xB1 = 0, xB2 = 0, tB0 = 0, tB1 = 0, tB2 = 0;
  const int pstartA = bA * na0;
  const int pstartB = bB * na0;
  if (spec && hasA && tid < na0) {
    const int n = pstartA + tid;
    xA0 = x[3 * n]; xA1 = x[3 * n + 1]; xA2 = x[3 * n + 2];
    tA0 = xt[3 * n]; tA1 = xt[3 * n + 1]; tA2 = xt[3 * n + 2];
  }
  if (spec && hasB && tid < na0) {
    const int n = pstartB + tid;
    xB0 = x[3 * n]; xB1 = x[3 * n + 1]; xB2 = x[3 * n + 2];
    tB0 = xt[3 * n]; tB1 = xt[3 * n + 1]; tB2 = xt[3 * n + 2];
  }
  float cA[9] = {0, 0, 0, 0, 0, 0, 0, 0, 0};
  float cB[9] = {0, 0, 0, 0, 0, 0, 0, 0, 0};
  if (hasA) {
#pragma unroll
    for (int i = 0; i < 9; ++i) cA[i] = cell[9 * bA + i];
  }
  if (hasB) {
#pragma unroll
    for (int i = 0; i < 9; ++i) cB[i] = cell[9 * bB + i];
  }

  // ---- triangular exclusive prefix: base = sum(na[0..blk)) ----
  int s = 0;
  const int nv = blk >> 2;  // exact: blk % 4 == 0
  const int4* na4 = (const int4*)na;
  for (int v = threadIdx.x; v < nv; v += BLOCK) {
    const int4 q = na4[v];
    s += q.x + q.y + q.z + q.w;
  }
  s = wave_sum_i(s);
  if (tid == 0) ired[wid] = s;

  // per-wave: the block's 16 structure sizes + 16-lane inclusive scan
  int nloc = 0;
  if (tid < SPB && blk + tid < B) nloc = na[blk + tid];
  int inc = nloc;
#pragma unroll
  for (int m = 1; m < SPB; m <<= 1) {
    const int u = __shfl_up(inc, m);
    if (tid >= m) inc += u;  // lanes >= 16 hold garbage, never read
  }
  __syncthreads();
  int base = 0;
#pragma unroll
  for (int w = 0; w < WPB; ++w) base += ired[w];

  const int laneA = 2 * wid, laneB = laneA + 1;
  const int nA = __shfl(nloc, laneA), incA = __shfl(inc, laneA);
  const int nB = __shfl(nloc, laneB), incB = __shfl(inc, laneB);
  const int startA = __builtin_amdgcn_readfirstlane(base + incA - nA);
  const int countA = __builtin_amdgcn_readfirstlane(nA);
  const int startB = __builtin_amdgcn_readfirstlane(base + incB - nB);
  const int countB = __builtin_amdgcn_readfirstlane(nB);

  const bool okA = spec && hasA && (startA == pstartA) && (countA == na0);
  const bool okB = spec && hasB && (startB == pstartB) && (countB == na0);

  const float ccA = cA[2] * cA[2] + cA[5] * cA[5] + cA[8] * cA[8];
  const float ccB = cB[2] * cB[2] + cB[5] * cB[5] + cB[8] * cB[8];

  float part = 0.f;
  if (okA) {
    part += structure_fast(cA, ccA, tid < countA, countA,
                           xA0, xA1, xA2, tA0, tA1, tA2);
  } else if (hasA && countA > 0) {
    part += structure_general(cA, ccA, x, xt, startA, countA, tid);
  }
  if (okB) {
    part += structure_fast(cB, ccB, tid < countB, countB,
                           xB0, xB1, xB2, tB0, tB1, tB2);
  } else if (hasB && countB > 0) {
    part += structure_general(cB, ccB, x, xt, startB, countB, tid);
  }

  part = wave_sum(part);
  if (tid == 0) wpart[wid] = part;
  __syncthreads();
  if (threadIdx.x == 0) {
    float t = 0.f;
#pragma unroll
    for (int w = 0; w < WPB; ++w) t += wpart[w];
    partial[blockIdx.x] = t;
  }
}

// Sum nparts floats (double accum) -> out = sum / (3*N).
__global__ __launch_bounds__(256) void mdl_final(const float* __restrict__ partial,
                                                 int nparts, float* __restrict__ out,
                                                 int N) {
  __shared__ double wsum[4];
  double s = 0.0;
  for (int i = threadIdx.x; i < nparts; i += 256) s += (double)partial[i];
#pragma unroll
  for (int m = 32; m >= 1; m >>= 1) s += __shfl_xor(s, m);
  if ((threadIdx.x & (WAVE - 1)) == 0) wsum[threadIdx.x / WAVE] = s;
  __syncthreads();
  if (threadIdx.x == 0) {
    double t = 0.0;
#pragma unroll
    for (int w = 0; w < 4; ++w) t += wsum[w];
    out[0] = (float)(t / (3.0 * (double)N));
  }
}

extern "C" void kernel_launch(void* const* d_in, const int* in_sizes, int n_in,
                              void* d_out, int out_size, void* d_ws, size_t ws_size,
                              hipStream_t stream) {
  const float* cell = (const float*)d_in[0];
  const float* x    = (const float*)d_in[1];
  const float* xt   = (const float*)d_in[2];
  const int*   na   = (const int*)d_in[3];
  const int B = in_sizes[3];
  const int N = in_sizes[1] / 3;

  const int nblocks = (B + SPB - 1) / SPB;
  float* partial = (float*)d_ws;  // nblocks floats

  mdl_main<<<nblocks, BLOCK, 0, stream>>>(cell, x, xt, na, partial, B, N);
  mdl_final<<<1, 256, 0, stream>>>(partial, nblocks, (float*)d_out, N);
}

// Round 11
// 17.121 us; speedup vs baseline: 6.3593x; 1.0418x over previous
//
#include <hip/hip_runtime.h>

#define WAVE 64
#define WPB 8                 // waves per block
#define SPB (2 * WPB)         // structures per block (2 per wave, consecutive)
#define BLOCK (WAVE * WPB)    // 512

// Wave-uniform per-structure constants: cell + Gram terms.
struct Pre {
  float c[9];
  float C00, C11, C22;        // |col0|^2, |col1|^2, |col2|^2
  float D01, D02, D12;        // 2 * (col_a . col_b)
};

__device__ __forceinline__ void make_pre(Pre& P) {
  P.C00 = P.c[0]*P.c[0] + P.c[3]*P.c[3] + P.c[6]*P.c[6];
  P.C11 = P.c[1]*P.c[1] + P.c[4]*P.c[4] + P.c[7]*P.c[7];
  P.C22 = P.c[2]*P.c[2] + P.c[5]*P.c[5] + P.c[8]*P.c[8];
  P.D01 = 2.f*(P.c[0]*P.c[1] + P.c[3]*P.c[4] + P.c[6]*P.c[7]);
  P.D02 = 2.f*(P.c[0]*P.c[2] + P.c[3]*P.c[5] + P.c[6]*P.c[8]);
  P.D12 = 2.f*(P.c[1]*P.c[2] + P.c[4]*P.c[5] + P.c[7]*P.c[8]);
}

// argmin over 27 periodic images, Gram-expanded:
// d(i,j,k) = rr - 2i g0 - 2j g1 - 2k g2 + i^2 C00 + j^2 C11 + k^2 C22
//            + ij D01 + ik D02 + jk D12,  r = cell@delta, g_a = r . col_a.
// Packed key (bits&~63)|o6 with o6 = (i+1)<<4 | (j+1)<<2 | (k+1): lexicographic
// order preserved (16 > 4*2+2), so min-key tie-break == jnp.argmin first-min.
// 64-ulp tie region + expansion rounding ~1e-6 << 7.9e-4 threshold; fmax clamp
// keeps near-zero d nonnegative so uint ordering is valid.
__device__ __forceinline__ int argmin_o(const Pre& P,
                                        float dd0, float dd1, float dd2) {
  const float r0 = P.c[0]*dd0 + P.c[1]*dd1 + P.c[2]*dd2;
  const float r1 = P.c[3]*dd0 + P.c[4]*dd1 + P.c[5]*dd2;
  const float r2 = P.c[6]*dd0 + P.c[7]*dd1 + P.c[8]*dd2;
  const float rr = r0*r0 + r1*r1 + r2*r2;
  const float g0 = r0*P.c[0] + r1*P.c[3] + r2*P.c[6];
  const float g1 = r0*P.c[1] + r1*P.c[4] + r2*P.c[7];
  const float g2 = r0*P.c[2] + r1*P.c[5] + r2*P.c[8];
  // 1-D terms A(i) = i^2*C00 - 2i*g0 etc.
  const float Am = fmaf(2.f, g0, P.C00), Ap = fmaf(-2.f, g0, P.C00);
  const float Bm = fmaf(2.f, g1, P.C11), Bp = fmaf(-2.f, g1, P.C11);
  const float Km = fmaf(2.f, g2, P.C22), Kp = fmaf(-2.f, g2, P.C22);
  const float BmpD = Bm + P.D01, BmmD = Bm - P.D01;
  const float BppD = Bp + P.D01, BpmD = Bp - P.D01;
  const float uS = P.D02 + P.D12, uD = P.D02 - P.D12;
  const float basem = rr + Am, basep = rr + Ap;

  unsigned best = 0xFFFFFFFFu;
  auto cell3 = [&](float pij, float u, unsigned ob) {
    // k=-1 -> ob+0 (d = pij + Km - u), k=0 -> ob+1, k=+1 -> ob+2 (pij + Kp + u)
    const float d0 = fmaxf(pij, 0.f);
    const float dp = fmaxf((pij + Kp) + u, 0.f);
    const float dm = fmaxf((pij + Km) - u, 0.f);
    const unsigned kk0 = (__float_as_uint(d0) & ~63u) | (ob + 1u);
    const unsigned kkp = (__float_as_uint(dp) & ~63u) | (ob + 2u);
    const unsigned kkm = (__float_as_uint(dm) & ~63u) | (ob + 0u);
    best = min(best, min(kk0, min(kkp, kkm)));
  };
  // rows i=-1,0,+1; cols j=-1,0,+1; u = i*D02 + j*D12
  cell3(basem + BmpD, -uS,     0u);        // i=-1 j=-1
  cell3(basem,        -P.D02,  4u);        // i=-1 j=0
  cell3(basem + BpmD, -uD,     8u);        // i=-1 j=+1
  cell3(rr + Bm,      -P.D12, 16u);        // i=0  j=-1
  cell3(rr,            0.f,   20u);        // i=0  j=0
  cell3(rr + Bp,       P.D12, 24u);        // i=0  j=+1
  cell3(basep + BmmD,  uD,    32u);        // i=+1 j=-1
  cell3(basep,         P.D02, 36u);        // i=+1 j=0
  cell3(basep + BppD,  uS,    40u);        // i=+1 j=+1
  return (int)(best & 63u);
}

__device__ __forceinline__ float wave_sum(float v) {
#pragma unroll
  for (int m = 32; m >= 1; m >>= 1) v += __shfl_xor(v, m);
  return v;
}

__device__ __forceinline__ int wave_sum_i(int v) {
#pragma unroll
  for (int m = 32; m >= 1; m >>= 1) v += __shfl_xor(v, m);
  return v;
}

// One structure, delta = x_tilde - x already in registers (count <= WAVE).
// s = off - delta.
__device__ __forceinline__ float structure_fast(const Pre& P, bool have, int count,
                                                float dd0, float dd1, float dd2) {
  float s0 = 0.f, s1 = 0.f, s2 = 0.f;
  if (have) {
    const int o = argmin_o(P, dd0, dd1, dd2);
    s0 = (float)(((o >> 4) & 3) - 1) - dd0;
    s1 = (float)(((o >> 2) & 3) - 1) - dd1;
    s2 = (float)((o & 3) - 1) - dd2;
  }
  const float sx = wave_sum(s0), sy = wave_sum(s1), sz = wave_sum(s2);
  const float inv = 1.0f / (float)count;
  const float cx = sx * inv, cy = sy * inv, cz = sz * inv;
  return have ? (fabsf(cx - s0) + fabsf(cy - s1) + fabsf(cz - s2)) : 0.f;
}

// General path (any count): stream atoms, recompute for the |.| pass.
__device__ __forceinline__ float structure_general(const Pre& P,
                                                   const float* __restrict__ x,
                                                   const float* __restrict__ xt,
                                                   int start, int count, int tid) {
  float sumx = 0.f, sumy = 0.f, sumz = 0.f;
  for (int n = start + tid; n < start + count; n += WAVE) {
    const float dd0 = xt[3*n] - x[3*n], dd1 = xt[3*n+1] - x[3*n+1],
                dd2 = xt[3*n+2] - x[3*n+2];
    const int o = argmin_o(P, dd0, dd1, dd2);
    sumx += (float)(((o >> 4) & 3) - 1) - dd0;
    sumy += (float)(((o >> 2) & 3) - 1) - dd1;
    sumz += (float)((o & 3) - 1) - dd2;
  }
  sumx = wave_sum(sumx); sumy = wave_sum(sumy); sumz = wave_sum(sumz);
  const float inv = 1.0f / (float)count;
  const float cx = sumx * inv, cy = sumy * inv, cz = sumz * inv;
  float part = 0.f;
  for (int n = start + tid; n < start + count; n += WAVE) {
    const float dd0 = xt[3*n] - x[3*n], dd1 = xt[3*n+1] - x[3*n+1],
                dd2 = xt[3*n+2] - x[3*n+2];
    const int o = argmin_o(P, dd0, dd1, dd2);
    const float s0 = (float)(((o >> 4) & 3) - 1) - dd0;
    const float s1 = (float)(((o >> 2) & 3) - 1) - dd1;
    const float s2 = (float)((o & 3) - 1) - dd2;
    part += fabsf(cx - s0) + fabsf(cy - s1) + fabsf(cz - s2);
  }
  return part;
}

// Block owns 16 consecutive structures (2/wave). Speculative coord prefetch
// (addresses predicted from na[0]) overlaps the triangular prefix scan;
// verified per-wave, general-path fallback on mismatch.
__global__ __launch_bounds__(BLOCK, 8) void mdl_main(const float* __restrict__ cell,
                                                     const float* __restrict__ x,
                                                     const float* __restrict__ xt,
                                                     const int* __restrict__ na,
                                                     float* __restrict__ partial,
                                                     int B, int N) {
  __shared__ int ired[WPB];
  __shared__ float wpart[WPB];
  const int wid = __builtin_amdgcn_readfirstlane(threadIdx.x / WAVE);
  const int tid = threadIdx.x % WAVE;
  const int blk = blockIdx.x * SPB;  // multiple of 16

  const int bA = blk + 2 * wid;
  const int bB = bA + 1;
  const bool hasA = bA < B;
  const bool hasB = bB < B;

  const int na0 = __builtin_amdgcn_readfirstlane(na[0]);
  const bool spec = (na0 > 0) && (na0 <= WAVE) &&
                    ((long)(blk + SPB) * (long)na0 <= (long)N);

  // speculative coord prefetch (deltas formed after loads land)
  float xA0 = 0, xA1 = 0, xA2 = 0, tA0 = 0, tA1 = 0, tA2 = 0;
  float xB0 = 0, xB1 = 0, xB2 = 0, tB0 = 0, tB1 = 0, tB2 = 0;
  const int pstartA = bA * na0;
  const int pstartB = bB * na0;
  if (spec && hasA && tid < na0) {
    const int n = pstartA + tid;
    xA0 = x[3*n]; xA1 = x[3*n+1]; xA2 = x[3*n+2];
    tA0 = xt[3*n]; tA1 = xt[3*n+1]; tA2 = xt[3*n+2];
  }
  if (spec && hasB && tid < na0) {
    const int n = pstartB + tid;
    xB0 = x[3*n]; xB1 = x[3*n+1]; xB2 = x[3*n+2];
    tB0 = xt[3*n]; tB1 = xt[3*n+1]; tB2 = xt[3*n+2];
  }
  Pre PA, PB;
#pragma unroll
  for (int i = 0; i < 9; ++i) PA.c[i] = hasA ? cell[9 * bA + i] : 0.f;
#pragma unroll
  for (int i = 0; i < 9; ++i) PB.c[i] = hasB ? cell[9 * bB + i] : 0.f;

  // triangular exclusive prefix: base = sum(na[0..blk))
  int s = 0;
  const int nv = blk >> 2;
  const int4* na4 = (const int4*)na;
  for (int v = threadIdx.x; v < nv; v += BLOCK) {
    const int4 q = na4[v];
    s += q.x + q.y + q.z + q.w;
  }
  s = wave_sum_i(s);
  if (tid == 0) ired[wid] = s;

  int nloc = 0;
  if (tid < SPB && blk + tid < B) nloc = na[blk + tid];
  int inc = nloc;
#pragma unroll
  for (int m = 1; m < SPB; m <<= 1) {
    const int u = __shfl_up(inc, m);
    if (tid >= m) inc += u;
  }
  __syncthreads();
  int base = 0;
#pragma unroll
  for (int w = 0; w < WPB; ++w) base += ired[w];

  const int laneA = 2 * wid, laneB = laneA + 1;
  const int nA = __shfl(nloc, laneA), incA = __shfl(inc, laneA);
  const int nB = __shfl(nloc, laneB), incB = __shfl(inc, laneB);
  const int startA = __builtin_amdgcn_readfirstlane(base + incA - nA);
  const int countA = __builtin_amdgcn_readfirstlane(nA);
  const int startB = __builtin_amdgcn_readfirstlane(base + incB - nB);
  const int countB = __builtin_amdgcn_readfirstlane(nB);

  const bool okA = spec && hasA && (startA == pstartA) && (countA == na0);
  const bool okB = spec && hasB && (startB == pstartB) && (countB == na0);

  make_pre(PA);
  make_pre(PB);

  float part = 0.f;
  if (okA) {
    part += structure_fast(PA, tid < countA, countA,
                           tA0 - xA0, tA1 - xA1, tA2 - xA2);
  } else if (hasA && countA > 0) {
    part += structure_general(PA, x, xt, startA, countA, tid);
  }
  if (okB) {
    part += structure_fast(PB, tid < countB, countB,
                           tB0 - xB0, tB1 - xB1, tB2 - xB2);
  } else if (hasB && countB > 0) {
    part += structure_general(PB, x, xt, startB, countB, tid);
  }

  part = wave_sum(part);
  if (tid == 0) wpart[wid] = part;
  __syncthreads();
  if (threadIdx.x == 0) {
    float t = 0.f;
#pragma unroll
    for (int w = 0; w < WPB; ++w) t += wpart[w];
    partial[blockIdx.x] = t;
  }
}

// Sum nparts floats (double accum) -> out = sum / (3*N).
__global__ __launch_bounds__(256) void mdl_final(const float* __restrict__ partial,
                                                 int nparts, float* __restrict__ out,
                                                 int N) {
  __shared__ double wsum[4];
  double s = 0.0;
  for (int i = threadIdx.x; i < nparts; i += 256) s += (double)partial[i];
#pragma unroll
  for (int m = 32; m >= 1; m >>= 1) s += __shfl_xor(s, m);
  if ((threadIdx.x & (WAVE - 1)) == 0) wsum[threadIdx.x / WAVE] = s;
  __syncthreads();
  if (threadIdx.x == 0) {
    double t = 0.0;
#pragma unroll
    for (int w = 0; w < 4; ++w) t += wsum[w];
    out[0] = (float)(t / (3.0 * (double)N));
  }
}

extern "C" void kernel_launch(void* const* d_in, const int* in_sizes, int n_in,
                              void* d_out, int out_size, void* d_ws, size_t ws_size,
                              hipStream_t stream) {
  const float* cell = (const float*)d_in[0];
  const float* x    = (const float*)d_in[1];
  const float* xt   = (const float*)d_in[2];
  const int*   na   = (const int*)d_in[3];
  const int B = in_sizes[3];
  const int N = in_sizes[1] / 3;

  const int nblocks = (B + SPB - 1) / SPB;
  float* partial = (float*)d_ws;  // nblocks floats

  mdl_main<<<nblocks, BLOCK, 0, stream>>>(cell, x, xt, na, partial, B, N);
  mdl_final<<<1, 256, 0, stream>>>(partial, nblocks, (float*)d_out, N);
}